// Round 1
// baseline (728.360 us; speedup 1.0000x reference)
//
#include <hip/hip_runtime.h>

// Problem constants
#define NPIX   32768      // B*H*W = 32*32*32
#define NEMB_  8192
#define EMB_   64
#define CH_    128
#define SPLIT  8
#define MCHUNK (NEMB_/SPLIT)   // 1024

// d_out layout (float elements):
//   [0, 2097152)           out       [B,E,H,W]
//   [2097152, 4194304)     z_q_flat  [B,H,W,E]   (also used as z_e scratch)
//   [4194304]              latent_loss (scalar)
//   [4194305, 4227073)     z_q_ind   [B,H,W] (as float)
#define OUT_OFF  0
#define ZQ_OFF   2097152
#define LOSS_OFF 4194304
#define IND_OFF  4194305

// ---------------------------------------------------------------------------
// K1: 1x1 conv projection.  z[b,c,hw] -> z_e[n,e], n = b*1024+hw
// block = 128 threads (one pixel each), grid = 256
__global__ __launch_bounds__(128) void k_proj(
    const float* __restrict__ z, const float* __restrict__ pw,
    const float* __restrict__ pb, float* __restrict__ z_e)
{
    __shared__ __align__(16) float wT[CH_ * EMB_];   // wT[c][e], 32 KB
    __shared__ __align__(16) float bs[EMB_];
    const int tid = threadIdx.x;
    for (int i = tid; i < CH_ * EMB_; i += 128) {
        int c = i >> 6, e = i & 63;
        wT[i] = pw[e * CH_ + c];
    }
    if (tid < EMB_) bs[tid] = pb[tid];
    __syncthreads();

    const int n  = blockIdx.x * 128 + tid;
    const int b  = n >> 10;
    const int hw = n & 1023;
    const float* zp = z + (size_t)b * (CH_ * 1024) + hw;

    float acc[EMB_];
    const float4* b4 = (const float4*)bs;
    #pragma unroll
    for (int i = 0; i < 16; i++) {
        float4 v = b4[i];
        acc[4*i] = v.x; acc[4*i+1] = v.y; acc[4*i+2] = v.z; acc[4*i+3] = v.w;
    }
    for (int c = 0; c < CH_; c++) {
        float zv = zp[(size_t)c * 1024];              // coalesced across lanes
        const float4* w4 = (const float4*)(wT + c * EMB_);  // LDS broadcast
        #pragma unroll
        for (int i = 0; i < 16; i++) {
            float4 v = w4[i];
            acc[4*i]   = fmaf(zv, v.x, acc[4*i]);
            acc[4*i+1] = fmaf(zv, v.y, acc[4*i+1]);
            acc[4*i+2] = fmaf(zv, v.z, acc[4*i+2]);
            acc[4*i+3] = fmaf(zv, v.w, acc[4*i+3]);
        }
    }
    float4* zo = (float4*)(z_e + (size_t)n * EMB_);
    #pragma unroll
    for (int i = 0; i < 16; i++)
        zo[i] = make_float4(acc[4*i], acc[4*i+1], acc[4*i+2], acc[4*i+3]);
}

// ---------------------------------------------------------------------------
// K1b: per-codebook-row squared norms
__global__ __launch_bounds__(256) void k_wsq(
    const float* __restrict__ ew, float* __restrict__ wsq)
{
    const int m = blockIdx.x * 256 + threadIdx.x;
    const float4* wr = (const float4*)(ew + (size_t)m * EMB_);
    float s = 0.f;
    #pragma unroll
    for (int i = 0; i < 16; i++) {
        float4 v = wr[i];
        s += v.x*v.x + v.y*v.y + v.z*v.z + v.w*v.w;
    }
    wsq[m] = s;
}

// ---------------------------------------------------------------------------
// K2: the hot kernel.  lane = pixel, m wave-uniform (scalar loads of embed row).
// grid = (128 pixel-blocks, SPLIT m-chunks), block = 256.
__global__ __launch_bounds__(256) void k_dist(
    const float* __restrict__ z_e, const float* __restrict__ ew,
    const float* __restrict__ wsq,
    float* __restrict__ pdist, int* __restrict__ pidx)
{
    const int n     = blockIdx.x * 256 + threadIdx.x;
    const int chunk = blockIdx.y;

    float x[EMB_];
    const float4* zr = (const float4*)(z_e + (size_t)n * EMB_);
    #pragma unroll
    for (int i = 0; i < 16; i++) {
        float4 v = zr[i];
        x[4*i] = v.x; x[4*i+1] = v.y; x[4*i+2] = v.z; x[4*i+3] = v.w;
    }

    float best = 3.0e38f;
    int   bi   = 0;
    const int m0 = chunk * MCHUNK;
    #pragma unroll 2
    for (int m = m0; m < m0 + MCHUNK; m++) {
        const float* wr = ew + (size_t)m * EMB_;   // uniform address -> s_load
        float a0 = 0.f, a1 = 0.f, a2 = 0.f, a3 = 0.f;
        #pragma unroll
        for (int e = 0; e < EMB_; e += 4) {
            a0 = fmaf(x[e],   wr[e],   a0);
            a1 = fmaf(x[e+1], wr[e+1], a1);
            a2 = fmaf(x[e+2], wr[e+2], a2);
            a3 = fmaf(x[e+3], wr[e+3], a3);
        }
        float dist = fmaf(-2.0f, (a0 + a1) + (a2 + a3), wsq[m]);
        if (dist < best) { best = dist; bi = m; }   // strict <: keeps lowest m
    }
    pdist[chunk * NPIX + n] = best;
    pidx [chunk * NPIX + n] = bi;
}

// ---------------------------------------------------------------------------
// K2b: combine the SPLIT partial argmins; write final idx (int + float out).
__global__ __launch_bounds__(256) void k_combine(
    const float* __restrict__ pdist, const int* __restrict__ pidx,
    int* __restrict__ fidx, float* __restrict__ out)
{
    const int n = blockIdx.x * 256 + threadIdx.x;
    float best = pdist[n];
    int   bi   = pidx[n];
    #pragma unroll
    for (int c = 1; c < SPLIT; c++) {
        float d = pdist[c * NPIX + n];
        int   i2 = pidx[c * NPIX + n];
        if (d < best) { best = d; bi = i2; }   // ascending chunks: first-min wins
    }
    fidx[n] = bi;
    out[IND_OFF + n] = (float)bi;
}

// ---------------------------------------------------------------------------
// K3: gather embeddings, write out (transposed) + z_q_flat, loss partials.
__global__ __launch_bounds__(256) void k_finalize(
    const int* __restrict__ fidx, const float* __restrict__ ew,
    float* __restrict__ out, float* __restrict__ lpart)
{
    const int tid = threadIdx.x;
    const int n   = blockIdx.x * 256 + tid;
    const int idx = fidx[n];
    const int b   = n >> 10;
    const int hw  = n & 1023;

    const float4* wr = (const float4*)(ew + (size_t)idx * EMB_);
    float4* zr = (float4*)(out + ZQ_OFF + (size_t)n * EMB_);   // holds z_e
    float* outp = out + OUT_OFF + (size_t)b * (EMB_ * 1024) + hw;

    float lsum = 0.f;
    #pragma unroll
    for (int i = 0; i < 16; i++) {
        float4 w4 = wr[i];
        float4 z4 = zr[i];
        float d0 = w4.x - z4.x, d1 = w4.y - z4.y;
        float d2 = w4.z - z4.z, d3 = w4.w - z4.w;
        lsum += d0*d0 + d1*d1 + d2*d2 + d3*d3;
        zr[i] = w4;                                   // z_q_flat
        outp[(4*i + 0) * 1024] = w4.x;                // out[b,e,hw], coalesced in hw
        outp[(4*i + 1) * 1024] = w4.y;
        outp[(4*i + 2) * 1024] = w4.z;
        outp[(4*i + 3) * 1024] = w4.w;
    }

    __shared__ float red[256];
    red[tid] = lsum;
    __syncthreads();
    if (tid < 128) red[tid] += red[tid + 128];
    __syncthreads();
    if (tid < 64) {
        float v = red[tid] + red[tid + 64];
        #pragma unroll
        for (int o = 32; o > 0; o >>= 1) v += __shfl_down(v, o);
        if (tid == 0) lpart[blockIdx.x] = v;
    }
}

// ---------------------------------------------------------------------------
// K4: final loss reduce (128 partials)
__global__ __launch_bounds__(64) void k_loss(
    const float* __restrict__ lpart, float* __restrict__ out)
{
    const int tid = threadIdx.x;
    float v = lpart[tid] + lpart[tid + 64];
    #pragma unroll
    for (int o = 32; o > 0; o >>= 1) v += __shfl_down(v, o);
    if (tid == 0)
        out[LOSS_OFF] = 12.5f * (v / 2097152.0f);   // 10*(0.25+1)*mean
}

// ---------------------------------------------------------------------------
extern "C" void kernel_launch(void* const* d_in, const int* in_sizes, int n_in,
                              void* d_out, int out_size, void* d_ws, size_t ws_size,
                              hipStream_t stream)
{
    const float* z  = (const float*)d_in[0];   // [32,128,32,32]
    const float* pw = (const float*)d_in[1];   // [64,128]
    const float* pb = (const float*)d_in[2];   // [64]
    const float* ew = (const float*)d_in[3];   // [8192,64]
    float* out = (float*)d_out;

    char* ws = (char*)d_ws;
    float* pdist = (float*)(ws);               // 8*32768*4 = 1 MB
    int*   pidx  = (int*)  (ws + 1048576);     // 1 MB
    int*   fidx  = (int*)  (ws + 2097152);     // 128 KB
    float* wsq   = (float*)(ws + 2228224);     // 32 KB
    float* lpart = (float*)(ws + 2260992);     // 512 B

    float* z_e = out + ZQ_OFF;                 // z_q_flat region doubles as z_e scratch

    hipLaunchKernelGGL(k_proj,     dim3(256),       dim3(128), 0, stream, z, pw, pb, z_e);
    hipLaunchKernelGGL(k_wsq,      dim3(32),        dim3(256), 0, stream, ew, wsq);
    hipLaunchKernelGGL(k_dist,     dim3(128, SPLIT),dim3(256), 0, stream, z_e, ew, wsq, pdist, pidx);
    hipLaunchKernelGGL(k_combine,  dim3(128),       dim3(256), 0, stream, pdist, pidx, fidx, out);
    hipLaunchKernelGGL(k_finalize, dim3(128),       dim3(256), 0, stream, fidx, ew, out, lpart);
    hipLaunchKernelGGL(k_loss,     dim3(1),         dim3(64),  0, stream, lpart, out);
}

// Round 2
// 281.946 us; speedup vs baseline: 2.5833x; 2.5833x over previous
//
#include <hip/hip_runtime.h>

// Problem constants
#define NPIX   32768      // B*H*W = 32*32*32
#define NEMB_  8192
#define EMB_   64
#define CH_    128
#define SPLIT  4          // code chunks (2048 codes each)

// d_out layout (float elements):
#define OUT_OFF  0
#define ZQ_OFF   2097152
#define LOSS_OFF 4194304
#define IND_OFF  4194305

typedef _Float16 h8  __attribute__((ext_vector_type(8)));
typedef float    f16f __attribute__((ext_vector_type(16)));

// ---------------------------------------------------------------------------
// K1: 1x1 conv projection.  z[b,c,hw] -> z_e[n,e]  (fp32, into ZQ region)
__global__ __launch_bounds__(128) void k_proj(
    const float* __restrict__ z, const float* __restrict__ pw,
    const float* __restrict__ pb, float* __restrict__ z_e)
{
    __shared__ __align__(16) float wT[CH_ * EMB_];
    __shared__ __align__(16) float bs[EMB_];
    const int tid = threadIdx.x;
    for (int i = tid; i < CH_ * EMB_; i += 128) {
        int c = i >> 6, e = i & 63;
        wT[i] = pw[e * CH_ + c];
    }
    if (tid < EMB_) bs[tid] = pb[tid];
    __syncthreads();

    const int n  = blockIdx.x * 128 + tid;
    const int b  = n >> 10;
    const int hw = n & 1023;
    const float* zp = z + (size_t)b * (CH_ * 1024) + hw;

    float acc[EMB_];
    const float4* b4 = (const float4*)bs;
    #pragma unroll
    for (int i = 0; i < 16; i++) {
        float4 v = b4[i];
        acc[4*i] = v.x; acc[4*i+1] = v.y; acc[4*i+2] = v.z; acc[4*i+3] = v.w;
    }
    for (int c = 0; c < CH_; c++) {
        float zv = zp[(size_t)c * 1024];
        const float4* w4 = (const float4*)(wT + c * EMB_);
        #pragma unroll
        for (int i = 0; i < 16; i++) {
            float4 v = w4[i];
            acc[4*i]   = fmaf(zv, v.x, acc[4*i]);
            acc[4*i+1] = fmaf(zv, v.y, acc[4*i+1]);
            acc[4*i+2] = fmaf(zv, v.z, acc[4*i+2]);
            acc[4*i+3] = fmaf(zv, v.w, acc[4*i+3]);
        }
    }
    float4* zo = (float4*)(z_e + (size_t)n * EMB_);
    #pragma unroll
    for (int i = 0; i < 16; i++)
        zo[i] = make_float4(acc[4*i], acc[4*i+1], acc[4*i+2], acc[4*i+3]);
}

// ---------------------------------------------------------------------------
// K1b: per-codebook-row squared norms (fp32 exact)
__global__ __launch_bounds__(256) void k_wsq(
    const float* __restrict__ ew, float* __restrict__ wsq)
{
    const int m = blockIdx.x * 256 + threadIdx.x;
    const float4* wr = (const float4*)(ew + (size_t)m * EMB_);
    float s = 0.f;
    #pragma unroll
    for (int i = 0; i < 16; i++) {
        float4 v = wr[i];
        s += v.x*v.x + v.y*v.y + v.z*v.z + v.w*v.w;
    }
    wsq[m] = s;
}

// ---------------------------------------------------------------------------
// Pack W' in MFMA-A fragment order.  K layout per code m (208 slots):
//   [0,64):   wh = fp16(w)
//   [64,128): wl*2^6,  wl = fp16(w - wh)
//   [128,192):wh*2^-6
//   192: s_hi = fp16(wsq)   193: s_lo = fp16(wsq - s_hi)   [194,208): 0
// Fragment order: W4[((tile*13 + s)*64 + lane)] : 8 halves for
//   code m = 32*tile + (lane&31),  k = 16*s + 8*(lane>>5) + j
__global__ __launch_bounds__(256) void k_prep_w(
    const float* __restrict__ ew, const float* __restrict__ wsq,
    float4* __restrict__ W4)
{
    const int id = blockIdx.x * 256 + threadIdx.x;   // 212992 total
    const int t  = id / 832;        // 13*64
    const int r  = id % 832;
    const int s  = r >> 6;
    const int l  = r & 63;
    const int m  = t * 32 + (l & 31);
    const int kb = s * 16 + ((l >> 5) << 3);
    const float* wr = ew + (size_t)m * EMB_;

    h8 h;
    #pragma unroll
    for (int j = 0; j < 8; j++) {
        const int kk = kb + j;
        _Float16 v;
        if (kk < 64) {
            v = (_Float16)wr[kk];
        } else if (kk < 128) {
            float x = wr[kk - 64];
            float xh = (float)(_Float16)x;
            v = (_Float16)((x - xh) * 64.0f);          // wl * 2^6
        } else if (kk < 192) {
            float xh = (float)(_Float16)wr[kk - 128];
            v = (_Float16)(xh * 0.015625f);            // wh * 2^-6
        } else if (kk == 192) {
            v = (_Float16)wsq[m];                      // s_hi
        } else if (kk == 193) {
            float q = wsq[m];
            float qh = (float)(_Float16)q;
            v = (_Float16)(q - qh);                    // s_lo
        } else {
            v = (_Float16)0.0f;
        }
        h[j] = v;
    }
    W4[id] = __builtin_bit_cast(float4, h);
}

// ---------------------------------------------------------------------------
// Pack X' in MFMA-B fragment order.  K layout per pixel n (208 slots):
//   [0,64):   xh      [64,128): xh*2^-6     [128,192): xl*2^6
//   192,193: -0.5     [194,208): 0
// Fragment order: X4[((tile*13 + s)*64 + lane)] : 8 halves for
//   pixel n = 32*tile + (lane&31),  k = 16*s + 8*(lane>>5) + j
__global__ __launch_bounds__(256) void k_prep_x(
    const float* __restrict__ z_e, float4* __restrict__ X4)
{
    const int id = blockIdx.x * 256 + threadIdx.x;   // 851968 total
    const int t  = id / 832;
    const int r  = id % 832;
    const int s  = r >> 6;
    const int l  = r & 63;
    const int n  = t * 32 + (l & 31);
    const int kb = s * 16 + ((l >> 5) << 3);
    const float* xr = z_e + (size_t)n * EMB_;

    h8 h;
    #pragma unroll
    for (int j = 0; j < 8; j++) {
        const int kk = kb + j;
        _Float16 v;
        if (kk < 64) {
            v = (_Float16)xr[kk];
        } else if (kk < 128) {
            float xh = (float)(_Float16)xr[kk - 64];
            v = (_Float16)(xh * 0.015625f);            // xh * 2^-6
        } else if (kk < 192) {
            float x = xr[kk - 128];
            float xh = (float)(_Float16)x;
            v = (_Float16)((x - xh) * 64.0f);          // xl * 2^6
        } else if (kk < 194) {
            v = (_Float16)(-0.5f);
        } else {
            v = (_Float16)0.0f;
        }
        h[j] = v;
    }
    X4[id] = __builtin_bit_cast(float4, h);
}

// ---------------------------------------------------------------------------
// K2: MFMA distance + fused argmax(acc) (== argmin dist, dist = -2*acc).
// Wave = 64 pixels (2 col-tiles of 32) x 2048 codes (64 row-tiles of 32).
// grid = (128 pixel-blocks, SPLIT chunks), block 256 (4 waves).
__global__ __launch_bounds__(256, 2) void k_mfma(
    const float4* __restrict__ X4, const float4* __restrict__ W4,
    float* __restrict__ pdist, int* __restrict__ pidx)
{
    const int lane  = threadIdx.x & 63;
    const int wv    = threadIdx.x >> 6;
    const int p0    = (blockIdx.x * 4 + wv) * 2;
    const int p1    = p0 + 1;
    const int chunk = blockIdx.y;

    // pixel B-fragments, held in registers for the whole kernel
    h8 b0[13], b1[13];
    #pragma unroll
    for (int s = 0; s < 13; s++) {
        b0[s] = __builtin_bit_cast(h8, X4[(p0 * 13 + s) * 64 + lane]);
        b1[s] = __builtin_bit_cast(h8, X4[(p1 * 13 + s) * 64 + lane]);
    }

    float bm0 = -3.0e38f, bm1 = -3.0e38f;
    int   bi0 = 0,        bi1 = 0;

    for (int t = 0; t < 64; t++) {
        const int ct = (chunk << 6) + t;
        const float4* wp = W4 + (size_t)ct * 832 + lane;
        float4 a4[13];
        #pragma unroll
        for (int s = 0; s < 13; s++) a4[s] = wp[s * 64];

        f16f acc0 = {0,0,0,0,0,0,0,0,0,0,0,0,0,0,0,0};
        f16f acc1 = {0,0,0,0,0,0,0,0,0,0,0,0,0,0,0,0};
        #pragma unroll
        for (int s = 0; s < 13; s++) {
            h8 a = __builtin_bit_cast(h8, a4[s]);
            acc0 = __builtin_amdgcn_mfma_f32_32x32x16_f16(a, b0[s], acc0, 0, 0, 0);
            acc1 = __builtin_amdgcn_mfma_f32_32x32x16_f16(a, b1[s], acc1, 0, 0, 0);
        }
        // C/D: col=lane&31 (pixel), row=(reg&3)+8*(reg>>2)+4*(lane>>5) (code)
        const int rb = (ct << 5) + ((lane >> 5) << 2);
        #pragma unroll
        for (int r2 = 0; r2 < 16; r2++) {
            const int row = rb + (r2 & 3) + ((r2 >> 2) << 3);  // ascending in r2
            float v0 = acc0[r2], v1 = acc1[r2];
            if (v0 > bm0) { bm0 = v0; bi0 = row; }   // strict >: lowest m wins
            if (v1 > bm1) { bm1 = v1; bi1 = row; }
        }
    }

    // each pixel's 32 rows are split across lane and lane^32: exchange
    float o0 = __shfl_xor(bm0, 32); int oi0 = __shfl_xor(bi0, 32);
    if (o0 > bm0 || (o0 == bm0 && oi0 < bi0)) { bm0 = o0; bi0 = oi0; }
    float o1 = __shfl_xor(bm1, 32); int oi1 = __shfl_xor(bi1, 32);
    if (o1 > bm1 || (o1 == bm1 && oi1 < bi1)) { bm1 = o1; bi1 = oi1; }

    int n; float bv; int bix;
    if (lane < 32) { n = (p0 << 5) + lane;        bv = bm0; bix = bi0; }
    else           { n = (p1 << 5) + (lane & 31); bv = bm1; bix = bi1; }
    pdist[chunk * NPIX + n] = bv;
    pidx [chunk * NPIX + n] = bix;
}

// ---------------------------------------------------------------------------
// K2b: combine SPLIT partial argmaxes (chunks ascending -> strict > keeps
// lowest index on ties).
__global__ __launch_bounds__(256) void k_combine(
    const float* __restrict__ pdist, const int* __restrict__ pidx,
    int* __restrict__ fidx, float* __restrict__ out)
{
    const int n = blockIdx.x * 256 + threadIdx.x;
    float best = pdist[n];
    int   bi   = pidx[n];
    #pragma unroll
    for (int c = 1; c < SPLIT; c++) {
        float d  = pdist[c * NPIX + n];
        int   i2 = pidx[c * NPIX + n];
        if (d > best) { best = d; bi = i2; }
    }
    fidx[n] = bi;
    out[IND_OFF + n] = (float)bi;
}

// ---------------------------------------------------------------------------
// K3: gather embeddings, write out (transposed) + z_q_flat, loss partials.
__global__ __launch_bounds__(256) void k_finalize(
    const int* __restrict__ fidx, const float* __restrict__ ew,
    float* __restrict__ out, float* __restrict__ lpart)
{
    const int tid = threadIdx.x;
    const int n   = blockIdx.x * 256 + tid;
    const int idx = fidx[n];
    const int b   = n >> 10;
    const int hw  = n & 1023;

    const float4* wr = (const float4*)(ew + (size_t)idx * EMB_);
    float4* zr = (float4*)(out + ZQ_OFF + (size_t)n * EMB_);   // holds z_e
    float* outp = out + OUT_OFF + (size_t)b * (EMB_ * 1024) + hw;

    float lsum = 0.f;
    #pragma unroll
    for (int i = 0; i < 16; i++) {
        float4 w4 = wr[i];
        float4 z4 = zr[i];
        float d0 = w4.x - z4.x, d1 = w4.y - z4.y;
        float d2 = w4.z - z4.z, d3 = w4.w - z4.w;
        lsum += d0*d0 + d1*d1 + d2*d2 + d3*d3;
        zr[i] = w4;
        outp[(4*i + 0) * 1024] = w4.x;
        outp[(4*i + 1) * 1024] = w4.y;
        outp[(4*i + 2) * 1024] = w4.z;
        outp[(4*i + 3) * 1024] = w4.w;
    }

    __shared__ float red[256];
    red[tid] = lsum;
    __syncthreads();
    if (tid < 128) red[tid] += red[tid + 128];
    __syncthreads();
    if (tid < 64) {
        float v = red[tid] + red[tid + 64];
        #pragma unroll
        for (int o = 32; o > 0; o >>= 1) v += __shfl_down(v, o);
        if (tid == 0) lpart[blockIdx.x] = v;
    }
}

// ---------------------------------------------------------------------------
__global__ __launch_bounds__(64) void k_loss(
    const float* __restrict__ lpart, float* __restrict__ out)
{
    const int tid = threadIdx.x;
    float v = lpart[tid] + lpart[tid + 64];
    #pragma unroll
    for (int o = 32; o > 0; o >>= 1) v += __shfl_down(v, o);
    if (tid == 0)
        out[LOSS_OFF] = 12.5f * (v / 2097152.0f);
}

// ---------------------------------------------------------------------------
extern "C" void kernel_launch(void* const* d_in, const int* in_sizes, int n_in,
                              void* d_out, int out_size, void* d_ws, size_t ws_size,
                              hipStream_t stream)
{
    const float* z  = (const float*)d_in[0];
    const float* pw = (const float*)d_in[1];
    const float* pb = (const float*)d_in[2];
    const float* ew = (const float*)d_in[3];
    float* out = (float*)d_out;

    // ws layout (bytes)
    char* ws = (char*)d_ws;
    float4* X4   = (float4*)(ws);                        // 851968*16 = 13,631,488
    float4* W4   = (float4*)(ws + 13631488);             // 212992*16 =  3,407,872
    float*  pdist= (float*) (ws + 17039360);             // 4*32768*4 =    524,288
    int*    pidx = (int*)   (ws + 17563648);             //                524,288
    int*    fidx = (int*)   (ws + 18087936);             //                131,072
    float*  wsq  = (float*) (ws + 18219008);             //                 32,768
    float*  lpart= (float*) (ws + 18251776);             //                    512

    float* z_e = out + ZQ_OFF;   // z_q_flat region doubles as z_e scratch

    hipLaunchKernelGGL(k_proj,    dim3(256),        dim3(128), 0, stream, z, pw, pb, z_e);
    hipLaunchKernelGGL(k_wsq,     dim3(32),         dim3(256), 0, stream, ew, wsq);
    hipLaunchKernelGGL(k_prep_w,  dim3(832),        dim3(256), 0, stream, ew, wsq, W4);
    hipLaunchKernelGGL(k_prep_x,  dim3(3328),       dim3(256), 0, stream, z_e, X4);
    hipLaunchKernelGGL(k_mfma,    dim3(128, SPLIT), dim3(256), 0, stream, X4, W4, pdist, pidx);
    hipLaunchKernelGGL(k_combine, dim3(128),        dim3(256), 0, stream, pdist, pidx, fidx, out);
    hipLaunchKernelGGL(k_finalize,dim3(128),        dim3(256), 0, stream, fidx, ew, out, lpart);
    hipLaunchKernelGGL(k_loss,    dim3(1),          dim3(64),  0, stream, lpart, out);
}